// Round 12
// baseline (276.350 us; speedup 1.0000x reference)
//
#include <hip/hip_runtime.h>
#include <cstddef>

#define NB 32
#define NN 2000
#define NRD 32
#define NE 128
#define NH 256
#define NA 8
#define KP8 2048         // conv K padded (fp8, BK=64)
#define NGP 128          // partial slots per batch
#define H1S 264          // h1 LDS tile stride (u16)
#define XT8S 136         // X fp8 LDS tile stride (bytes): 34 dw -> <=2-way banks
#define ACTION_NORM 2000.0f

typedef unsigned short u16;
typedef unsigned char u8;
typedef __bf16 b16x8 __attribute__((ext_vector_type(8)));
typedef float f32x4 __attribute__((ext_vector_type(4)));
typedef const __attribute__((address_space(1))) unsigned int* gptr_t;
typedef __attribute__((address_space(3))) unsigned int* lptr_t;

__device__ inline u16 f2bf(float x) {
    unsigned u = __float_as_uint(x);
    u += 0x7FFFu + ((u >> 16) & 1u);
    return (u16)(u >> 16);
}
__device__ inline float bf2f(u16 h) { return __uint_as_float((unsigned)h << 16); }
__device__ inline u8 f2fp8(float x) {
    return (u8)(__builtin_amdgcn_cvt_pk_fp8_f32(x, x, 0, false) & 0xFF);
}
__device__ inline u16 f2fp8x2(float a, float b) {
    return (u16)(__builtin_amdgcn_cvt_pk_fp8_f32(a, b, 0, false) & 0xFFFF);
}
__device__ inline float fp82f(u8 b) {
    return __builtin_amdgcn_cvt_pk_f32_fp8((unsigned)b, false)[0];
}
// fp8 K-swizzle for conv staging (R10-verified conflict-free b128 reads)
__device__ inline int kswz(int m) {
    return (m & ~63) + (((m >> 3) & 3) << 4) + (((m >> 5) & 1) << 3) + (m & 7);
}

// ---------------------------------------------------------------- front: prep + dm partial max + actions/ap0/part0 init
#define PREP_STATE (64000 * 32)
#define PREP_W1T   (256 * 32)
#define PREP_W2T   (128 * 256)
#define PREP_WQ1T  (256 * 128)
#define PREP_PAD   (4096 * 48)
#define PREP_TOT   (PREP_STATE + PREP_W1T + PREP_W2T + PREP_WQ1T + PREP_PAD)
#define PREP_BLOCKS (PREP_TOT / 256)       // 9056
#define MAX_BLOCKS 1024
__global__ __launch_bounds__(256) void k_front(
        const float* __restrict__ state, const float* __restrict__ W1,
        const float* __restrict__ W2, const float* __restrict__ Wq1,
        const float* __restrict__ dm, const int* __restrict__ fa,
        const int* __restrict__ fid,
        u16* __restrict__ state_b, u16* __restrict__ W1t,
        u16* __restrict__ W2t, u8* __restrict__ Wq1f8,
        u8* __restrict__ encb, float* __restrict__ pmax,
        float* __restrict__ actions, float* __restrict__ ap0,
        float2* __restrict__ part0) {
    __shared__ float sh[256];
    const int blk = blockIdx.x, t = threadIdx.x;
    if (blk < PREP_BLOCKS) {
        int i = blk * 256 + t;
        if (i < PREP_STATE) { state_b[i] = f2bf(state[i]); return; }
        i -= PREP_STATE;
        if (i < PREP_W1T) { int h = i >> 5, k = i & 31; W1t[i] = f2bf(W1[k * NH + h]); return; }
        i -= PREP_W1T;
        if (i < PREP_W2T) { int e = i >> 8, h = i & 255; W2t[i] = f2bf(W2[h * NE + e]); return; }
        i -= PREP_W2T;
        if (i < PREP_WQ1T) { int hq = i >> 7, e = i & 127; Wq1f8[i] = f2fp8(Wq1[e * NH + hq]); return; }
        i -= PREP_WQ1T;
        if (i < PREP_PAD) { int eb = i / 48, mm = NN + (i % 48); encb[(size_t)eb * KP8 + kswz(mm)] = 0; }
        return;
    }
    if (blk < PREP_BLOCKS + MAX_BLOCKS) {
        const int bid = blk - PREP_BLOCKS;
        float m = 0.0f;
        for (size_t i = (size_t)bid * 256 + t; i < (size_t)NN * NN; i += (size_t)MAX_BLOCKS * 256)
            m = fmaxf(m, dm[i]);
        sh[t] = m; __syncthreads();
        for (int s = 128; s > 0; s >>= 1) {
            if (t < s) sh[t] = fmaxf(sh[t], sh[t + s]);
            __syncthreads();
        }
        if (t == 0) pmax[bid] = sh[0];
        return;
    }
    // last block: actions init + agent-0 ap + zero part0
    const int b = t >> 3, a = t & 7;
    float v = -1.0f;
    for (int j = 0; j < 3; ++j)
        if (fid[j] == a) v = (float)fa[j * NB + b] / ACTION_NORM;
    actions[t] = v;
    sh[t] = v;
    __syncthreads();
    float wq[NA];
#pragma unroll
    for (int aa = 0; aa < NA; ++aa) wq[aa] = Wq1[(size_t)(NE + aa) * NH + t];
    for (int bb = 0; bb < NB; ++bb) {
        float s = 0.0f;
#pragma unroll
        for (int aa = 0; aa < NA; ++aa) s = fmaf(sh[bb * NA + aa], wq[aa], s);
        ap0[bb * NH + t] = s;
    }
    for (int i = t; i < NB * NGP; i += 256) part0[i] = make_float2(0.0f, 0.0f);
}

// ---------------------------------------------------------------- sim: row-softmax-prep of distance matrix (grid 2000)
__global__ __launch_bounds__(512) void k_sim(
        const float* __restrict__ dm, const float* __restrict__ pmax,
        u8* __restrict__ simb, float* __restrict__ inv_rs) {
    __shared__ float shf[512];
    __shared__ u8 srow[KP8];
    const int n = blockIdx.x, t = threadIdx.x;
    float m = fmaxf(pmax[t], pmax[t + 512]);
    shf[t] = m; __syncthreads();
    for (int s = 256; s > 0; s >>= 1) {
        if (t < s) shf[t] = fmaxf(shf[t], shf[t + s]);
        __syncthreads();
    }
    const float inv = 1.0f / shf[0];
    __syncthreads();
    float s = 0.0f;
    for (int mm = t * 2; mm < KP8; mm += 1024) {
        float e0 = 0.0f, e1 = 0.0f;
        if (mm < NN)     { e0 = expf(-dm[(size_t)n * NN + mm] * inv);     s += e0; }
        if (mm + 1 < NN) { e1 = expf(-dm[(size_t)n * NN + mm + 1] * inv); s += e1; }
        *(u16*)(srow + kswz(mm)) = f2fp8x2(e0, e1);
    }
    shf[t] = s; __syncthreads();
    for (int st = 256; st > 0; st >>= 1) {
        if (t < st) shf[t] += shf[t + st];
        __syncthreads();
    }
    if (t == 0) inv_rs[n] = 1.0f / shf[0];
    // coalesced row store (srow visible via the reduction-tree barriers)
    if (t < 128) *(uint4*)(simb + (size_t)n * KP8 + t * 16) = *(const uint4*)(srow + t * 16);
}

// ---------------------------------------------------------------- enc: fused enc1+enc2 (grid 1000)
__global__ __launch_bounds__(512) void k_enc(
        const u16* __restrict__ state_b, const u16* __restrict__ W1t,
        const u16* __restrict__ W2t, u8* __restrict__ encb,
        const float* __restrict__ b1, const float* __restrict__ b2) {
    __shared__ u16 stage[20 * 512];        // 20 KB staging (phase2: 2x 8KB dbuf; epilogue: 8KB etile)
    __shared__ u16 h1t[64 * H1S];          // 33 KB h1 tile
    const int blk = blockIdx.x, tid = threadIdx.x;
    const int w = tid >> 6, l = tid & 63;
    const int lm = l & 15, lq = l >> 4;
    const int gm = blk * 64;

    // ---- phase 1: h1 tile (M=64, N=256, K=32).
    {
#pragma unroll
        for (int i = 0; i < 3; ++i) {
            const int idx = w * 3 + i;
            if (idx < 20) {
                const u16* gp;
                if (idx < 4) gp = state_b + (size_t)(gm + idx * 16 + lm) * NRD + lq * 8;
                else         gp = W1t + (size_t)((idx - 4) * 16 + lm) * NRD + lq * 8;
                __builtin_amdgcn_global_load_lds((gptr_t)gp, (lptr_t)(stage + idx * 512), 16, 0, 0);
            }
        }
        __syncthreads();
        b16x8 af[4], bf[2];
#pragma unroll
        for (int i = 0; i < 4; ++i) af[i] = *(const b16x8*)(stage + i * 512 + l * 8);
#pragma unroll
        for (int j = 0; j < 2; ++j) bf[j] = *(const b16x8*)(stage + (4 + w * 2 + j) * 512 + l * 8);
        f32x4 acc1[4][2] = {};
#pragma unroll
        for (int i = 0; i < 4; ++i)
#pragma unroll
            for (int j = 0; j < 2; ++j)
                acc1[i][j] = __builtin_amdgcn_mfma_f32_16x16x32_bf16(af[i], bf[j], acc1[i][j], 0, 0, 0);
#pragma unroll
        for (int i = 0; i < 4; ++i)
#pragma unroll
            for (int r = 0; r < 4; ++r) {
                const int row = i * 16 + lq * 4 + r;
#pragma unroll
                for (int j = 0; j < 2; ++j) {
                    const int col = w * 32 + j * 16 + lm;
                    h1t[row * H1S + col] = f2bf(fmaxf(acc1[i][j][r] + b1[col], 0.0f));
                }
            }
    }

    // ---- phase 2: enc tile (M=128 e, N=64 m, K=256), A=W2t staged (2-phase dbuf), B=h1t LDS.
    const int wr = w & 3, wc = w >> 2;
    f32x4 acc2[2][2] = {};
    const u16* gpw = W2t + (size_t)(w * 16 + lm) * NH + lq * 8;
    __syncthreads();   // phase-1 stage reads done before overwrite
    __builtin_amdgcn_global_load_lds((gptr_t)gpw, (lptr_t)(stage + w * 512), 16, 0, 0);
    __syncthreads();   // buf0 ready (+ h1t visible)
    for (int t = 0; t < 8; ++t) {
        const int cur = t & 1;
        if (t < 7) {
            gpw += 32;
            __builtin_amdgcn_global_load_lds((gptr_t)gpw,
                (lptr_t)(stage + (cur ^ 1) * 4096 + w * 512), 16, 0, 0);
        }
        const u16* base = stage + cur * 4096;
        b16x8 af2[2], bf2[2];
#pragma unroll
        for (int i = 0; i < 2; ++i)
            af2[i] = *(const b16x8*)(base + (wr * 2 + i) * 512 + l * 8);
#pragma unroll
        for (int j = 0; j < 2; ++j)
            bf2[j] = *(const b16x8*)(h1t + (wc * 32 + j * 16 + lm) * H1S + t * 32 + lq * 8);
#pragma unroll
        for (int i = 0; i < 2; ++i)
#pragma unroll
            for (int j = 0; j < 2; ++j)
                acc2[i][j] = __builtin_amdgcn_mfma_f32_16x16x32_bf16(af2[i], bf2[j], acc2[i][j], 0, 0, 0);
        __syncthreads();
    }

    // ---- epilogue: stage fp8 tile [e:128][off:64] in LDS, then coalesced writes.
    u8* etile = (u8*)stage;            // 8 KB, stage is dead after the loop's final barrier
#pragma unroll
    for (int i = 0; i < 2; ++i)
#pragma unroll
        for (int r = 0; r < 4; ++r) {
            const int e = wr * 32 + i * 16 + lq * 4 + r;
            const float bias = b2[e];
#pragma unroll
            for (int j = 0; j < 2; ++j) {
                const int off = wc * 32 + j * 16 + lm;
                etile[e * 64 + off] = f2fp8(acc2[i][j][r] + bias);
            }
        }
    __syncthreads();
#pragma unroll
    for (int u0 = 0; u0 < 2; ++u0) {
        const int u = u0 * 512 + tid;          // 1024 units: e = u>>3, run = u&7
        const int e = u >> 3, run = u & 7;
        const int rg0 = gm + run * 8;
        const unsigned bb = (unsigned)rg0 / 2000u;
        const unsigned m0 = (unsigned)rg0 - bb * 2000u;   // 8-aligned
        const int wbyte = (int)(m0 & ~63u) + (int)(((m0 >> 3) & 3u) << 4) + (int)(((m0 >> 5) & 1u) << 3);
        const uint2 v = *(const uint2*)(etile + e * 64 + run * 8);
        *(uint2*)(encb + ((size_t)bb * 128 + e) * KP8 + wbyte) = v;
    }
}

// ---------------------------------------------------------------- fused conv + y0 + agent-0 softmax partials
// grid (16,32), 128-row tiles, XCD-aware bijective swizzle (R8: FETCH 35->16.5 MB).
// Phase 1 is REGISTER-STAGED: the old LDS staging was lane-linear pass-through
// (lane l's fragment == global[row(lm)*KP8 + kt*64 + lq*16] byte-for-byte), so
// each wave loads its 6 fragments (4A+2B, 16B/lane) global->VGPR directly.
// NO barriers, NO LDS, NO explicit waitcnt in the K-loop: each wave runs a
// compiler-scheduled load(t+1)/compute(t) pipeline and the 16 waves/CU drift
// freely -> TLP hides L2 latency (R11 diagnosis: barrier lockstep was the
// ~3300cyc/step critical path with every pipe < 40%).
__global__ __launch_bounds__(512) void k_conv_y0(
        const u8* __restrict__ simb, const u8* __restrict__ encb,
        const u8* __restrict__ Wq1f8, const float* __restrict__ inv_rs,
        const float* __restrict__ bq1, const float* __restrict__ ap0,
        const float* __restrict__ Wq2, u8* __restrict__ y0f8,
        float2* __restrict__ part0) {
    __shared__ u8 xt8[128 * XT8S];          // 17.4 KB X tile (fp8)
    __shared__ float qsum[64 * 8];          // 2 KB per-row wave partials
    const int tid = threadIdx.x;
    const int w = tid >> 6, l = tid & 63;   // 8 waves
    const int wr = w & 1, wc = w >> 1;      // wc in [0,4)
    // ---- XCD-aware bijective block remap
    const int L = blockIdx.x + (int)(blockIdx.y << 4);
    const int g = L & 7, ii = L >> 3;
    const int bx = (g & 1) * 8 + (ii & 7);       // node tile 0..15
    const int by = (g >> 1) * 8 + (ii >> 3);     // batch 0..31
    const int bm = bx * 128;
    const int bb = by;
    const int lm = l & 15, lq = l >> 4;
    const u8* Bt = encb + (size_t)bb * 128 * KP8;
    typedef long lx2 __attribute__((ext_vector_type(2)));

    f32x4 acc[4][2] = {};

    // per-lane global fragment base pointers (same bytes the LDS path delivered)
    const u8* gpa[4];
    const u8* gpb[2];
#pragma unroll
    for (int i = 0; i < 4; ++i) {
        int row = bm + (wr * 4 + i) * 16 + lm;
        row = row < NN ? row : NN - 1;
        gpa[i] = simb + (size_t)row * KP8 + lq * 16;
    }
#pragma unroll
    for (int j = 0; j < 2; ++j)
        gpb[j] = Bt + (size_t)((wc * 2 + j) * 16 + lm) * KP8 + lq * 16;

    struct frag_t { lx2 a[4]; lx2 b[2]; };
    auto LOADF = [&](frag_t& f, int kt) {
#pragma unroll
        for (int i = 0; i < 4; ++i) f.a[i] = *(const lx2*)(gpa[i] + kt * 64);
#pragma unroll
        for (int j = 0; j < 2; ++j) f.b[j] = *(const lx2*)(gpb[j] + kt * 64);
    };
    auto COMPUTE = [&](const frag_t& f) {
        __builtin_amdgcn_s_setprio(1);
#pragma unroll
        for (int i = 0; i < 4; ++i)
#pragma unroll
            for (int j = 0; j < 2; ++j) {
                acc[i][j] = __builtin_amdgcn_mfma_f32_16x16x32_fp8_fp8(f.a[i][0], f.b[j][0], acc[i][j], 0, 0, 0);
                acc[i][j] = __builtin_amdgcn_mfma_f32_16x16x32_fp8_fp8(f.a[i][1], f.b[j][1], acc[i][j], 0, 0, 0);
            }
        __builtin_amdgcn_s_setprio(0);
    };

    // depth-1 software pipeline, 2x unrolled (named stages: rule #20)
    frag_t f0, f1;
    LOADF(f0, 0);
    for (int t = 0; t < 30; t += 2) {
        LOADF(f1, t + 1); COMPUTE(f0);     // tile t
        LOADF(f0, t + 2); COMPUTE(f1);     // tile t+1
    }
    LOADF(f1, 31); COMPUTE(f0);            // tile 30
    COMPUTE(f1);                           // tile 31

    // ---- epilogue 1: scaled X tile -> fp8 LDS
#pragma unroll
    for (int i = 0; i < 4; ++i) {
#pragma unroll
        for (int r = 0; r < 4; ++r) {
            const int row = wr * 64 + i * 16 + lq * 4 + r;
            const int gn = bm + row;
            const float rsv = inv_rs[gn < NN ? gn : NN - 1];
#pragma unroll
            for (int j = 0; j < 2; ++j) {
                const int col = wc * 32 + j * 16 + lm;
                xt8[row * XT8S + col] = f2fp8(acc[i][j][r] * rsv);
            }
        }
    }
    __syncthreads();

    // ---- phase 2+3: y0 (fp8 MFMA) + agent-0 q partials
    const int h0 = w * 32;
    float bq1v[2], apv[2], w2vv[2];
#pragma unroll
    for (int j = 0; j < 2; ++j) {
        const int h = h0 + j * 16 + lm;
        bq1v[j] = bq1[h];
        apv[j] = ap0[bb * NH + h];
        w2vv[j] = Wq2[h];
    }
    float se_tot = 0.0f, sn_tot = 0.0f;

    for (int half = 0; half < 2; ++half) {
        f32x4 acc2[4][2] = {};
#pragma unroll
        for (int ks = 0; ks < 4; ++ks) {
            long bfw[2];
#pragma unroll
            for (int j = 0; j < 2; ++j)
                bfw[j] = *(const long*)(Wq1f8 + (size_t)(h0 + j * 16 + lm) * NE + ks * 32 + lq * 8);
#pragma unroll
            for (int i = 0; i < 4; ++i) {
                const long afx = *(const long*)(xt8 + (half * 64 + i * 16 + lm) * XT8S + ks * 32 + lq * 8);
#pragma unroll
                for (int j = 0; j < 2; ++j)
                    acc2[i][j] = __builtin_amdgcn_mfma_f32_16x16x32_fp8_fp8(afx, bfw[j], acc2[i][j], 0, 0, 0);
            }
        }
#pragma unroll
        for (int i = 0; i < 4; ++i) {
#pragma unroll
            for (int r = 0; r < 4; ++r) {
                const int rl = i * 16 + lq * 4 + r;
                const int n = bm + half * 64 + rl;
                float q = 0.0f;
#pragma unroll
                for (int j = 0; j < 2; ++j) {
                    const float v = acc2[i][j][r] + bq1v[j];
                    if (n < NN) y0f8[((size_t)n * NB + bb) * NH + h0 + j * 16 + lm] = f2fp8(v);
                    q += fmaxf(v + apv[j], 0.0f) * w2vv[j];
                }
#pragma unroll
                for (int off = 1; off < 16; off <<= 1) q += __shfl_xor(q, off);
                if (lm == 0) qsum[rl * 8 + w] = q;
            }
        }
        __syncthreads();
        if (tid < 64) {
            const int n = bm + half * 64 + tid;
            float q = 0.0f;
#pragma unroll
            for (int wv = 0; wv < 8; ++wv) q += qsum[tid * 8 + wv];
            float e = (n < NN) ? expf(fminf(q, 60.0f)) : 0.0f;
            float sne = e * (float)n;
#pragma unroll
            for (int off = 32; off > 0; off >>= 1) {
                e += __shfl_xor(e, off); sne += __shfl_xor(sne, off);
            }
            if (tid == 0) { se_tot += e; sn_tot += sne; }
        }
        __syncthreads();
    }
    if (tid == 0) part0[bb * NGP + bx] = make_float2(se_tot, sn_tot);
}

// ---------------------------------------------------------------- per-agent kernel (ag = 1..7)
// y0f8 padded to 2048 rows: 4 unconditional main-loop loads hoisted to the TOP
// (independent of the pin reduce -> overlap HBM latency with the reduction).
// ap16 = apb (carried projection) + d * Wq1[agent row] (R7-verified).
__global__ __launch_bounds__(256) void k_agent(
        const u8* __restrict__ y0f8, const float* __restrict__ Wq1,
        const float* __restrict__ Wq2, const float* __restrict__ bq2,
        float* actions, const int* __restrict__ fa, const int* __restrict__ fid,
        const float* __restrict__ apb, float* __restrict__ apbase_out,
        const float2* __restrict__ pin, float2* __restrict__ pout,
        float* __restrict__ out, int ag) {
    __shared__ float sh[256];
    __shared__ float s_sam;
    const int t = threadIdx.x;
    const int lane = t & 63, wave = t >> 6;
    const int wg = blockIdx.x * 4 + wave;
    const int b = wg & 31, ng = wg >> 5;        // ng in [0,128)
    const int hl = lane & 15, qtr = lane >> 4;
    const int idx = ag - 1;

    // ---- y0 loads FIRST (no dependency on pin): HBM latency overlaps reduce
    uint4 yv[4];
#pragma unroll
    for (int k = 0; k < 4; ++k) {
        const int n = 4 * (ng + k * NGP) + qtr;     // < 2048 (padded)
        yv[k] = *(const uint4*)(y0f8 + (((size_t)n * NB + b) << 8) + hl * 16);
    }

    float samn;
    {
        const float2 p0 = pin[b * NGP + lane];
        const float2 p1 = pin[b * NGP + 64 + lane];
        float se0 = p0.x + p1.x, sn0 = p0.y + p1.y;
#pragma unroll
        for (int m = 32; m > 0; m >>= 1) {
            se0 += __shfl_xor(se0, m); sn0 += __shfl_xor(sn0, m);
        }
        const float sam = fminf(fmaxf(sn0 / se0, 0.0f), 2000.0f);
        samn = sam * (1.0f / ACTION_NORM);
    }
    // initial action value for this agent slot (never yet written to actions[])
    float iv = -1.0f;
    for (int j = 0; j < 3; ++j)
        if (fid[j] == idx) iv = (float)fa[j * NB + b] * (1.0f / ACTION_NORM);
    const float d = samn - iv;

    float ap16[16], w2v[16];
    {
        const float4* ab  = (const float4*)(apb + b * NH + hl * 16);
        const float4* wq  = (const float4*)(Wq1 + (size_t)(NE + idx) * NH + hl * 16);
        const float4* w2p = (const float4*)(Wq2 + hl * 16);
#pragma unroll
        for (int jj = 0; jj < 4; ++jj) {
            const float4 a4 = ab[jj]; const float4 w4 = wq[jj]; const float4 v4 = w2p[jj];
            ap16[jj * 4 + 0] = fmaf(d, w4.x, a4.x);
            ap16[jj * 4 + 1] = fmaf(d, w4.y, a4.y);
            ap16[jj * 4 + 2] = fmaf(d, w4.z, a4.z);
            ap16[jj * 4 + 3] = fmaf(d, w4.w, a4.w);
            w2v[jj * 4 + 0] = v4.x; w2v[jj * 4 + 1] = v4.y;
            w2v[jj * 4 + 2] = v4.z; w2v[jj * 4 + 3] = v4.w;
        }
    }

    float se = 0.0f, sn = 0.0f;
#pragma unroll
    for (int k = 0; k < 4; ++k) {
        const int n = 4 * (ng + k * NGP) + qtr;
        const unsigned dw[4] = {yv[k].x, yv[k].y, yv[k].z, yv[k].w};
        float q = 0.0f;
#pragma unroll
        for (int dd = 0; dd < 4; ++dd) {
            const auto lo = __builtin_amdgcn_cvt_pk_f32_fp8(dw[dd], false);
            const auto hi = __builtin_amdgcn_cvt_pk_f32_fp8(dw[dd], true);
            q += fmaxf(lo[0] + ap16[dd * 4 + 0], 0.f) * w2v[dd * 4 + 0];
            q += fmaxf(lo[1] + ap16[dd * 4 + 1], 0.f) * w2v[dd * 4 + 1];
            q += fmaxf(hi[0] + ap16[dd * 4 + 2], 0.f) * w2v[dd * 4 + 2];
            q += fmaxf(hi[1] + ap16[dd * 4 + 3], 0.f) * w2v[dd * 4 + 3];
        }
#pragma unroll
        for (int off = 1; off < 16; off <<= 1) q += __shfl_xor(q, off);
        if (n < NN) {
            const float e = expf(fminf(q, 60.0f));
            se += e; sn += e * (float)n;
        }
    }
    se += __shfl_xor(se, 16); sn += __shfl_xor(sn, 16);
    se += __shfl_xor(se, 32); sn += __shfl_xor(sn, 32);
    if (lane == 0) pout[b * NGP + ng] = make_float2(se, sn);

    if (blockIdx.x < NB) {
        const int bb = blockIdx.x;
        if (wave == 0) {
            const float2 p0 = pin[bb * NGP + lane];
            const float2 p1 = pin[bb * NGP + 64 + lane];
            float a1 = p0.x + p1.x, a2 = p0.y + p1.y;
#pragma unroll
            for (int m = 32; m > 0; m >>= 1) {
                a1 += __shfl_xor(a1, m); a2 += __shfl_xor(a2, m);
            }
            if (lane == 0) s_sam = fminf(fmaxf(a2 / a1, 0.0f), 2000.0f);
        }
        __syncthreads();
        const float sam = s_sam;
        const float samf = sam * (1.0f / ACTION_NORM);
        float apt = 0.0f;
#pragma unroll
        for (int a = 0; a < NA; ++a) {
            const float av = (a == idx) ? samf : actions[bb * NA + a];
            apt = fmaf(av, Wq1[(size_t)(NE + a) * NH + t], apt);
        }
        apbase_out[bb * NH + t] = apt;          // carried projection for stage ag+1
        int nsel = (int)sam; if (nsel > NN - 1) nsel = NN - 1;
        const float yv2 = fp82f(y0f8[((size_t)nsel * NB + bb) * NH + t]);
        sh[t] = fmaxf(yv2 + apt, 0.0f) * Wq2[t];
        __syncthreads();
        for (int s = 128; s > 0; s >>= 1) {
            if (t < s) sh[t] += sh[t + s];
            __syncthreads();
        }
        if (t == 0) {
            out[bb * NA + idx] = sh[0] + bq2[0];
            actions[bb * NA + idx] = samf;
        }
    }
}

// ---------------------------------------------------------------- tail: finalize agent 7 + chosen
__global__ __launch_bounds__(256) void k_fin(
        const u8* __restrict__ y0f8, const float* __restrict__ Wq1,
        const float* __restrict__ Wq2, const float* __restrict__ bq2,
        const float* __restrict__ actions, const float2* __restrict__ pin,
        float* __restrict__ out) {
    __shared__ float sh[256];
    __shared__ float s_sam;
    const int bb = blockIdx.x, t = threadIdx.x;
    const int lane = t & 63, wave = t >> 6;
    if (wave == 0) {
        const float2 p0 = pin[bb * NGP + lane];
        const float2 p1 = pin[bb * NGP + 64 + lane];
        float a1 = p0.x + p1.x, a2 = p0.y + p1.y;
#pragma unroll
        for (int m = 32; m > 0; m >>= 1) {
            a1 += __shfl_xor(a1, m); a2 += __shfl_xor(a2, m);
        }
        if (lane == 0) s_sam = fminf(fmaxf(a2 / a1, 0.0f), 2000.0f);
    }
    __syncthreads();
    const float sam = s_sam;
    const float samn = sam * (1.0f / ACTION_NORM);
    float apt = 0.0f;
#pragma unroll
    for (int a = 0; a < NA; ++a) {
        const float av = (a == NA - 1) ? samn : actions[bb * NA + a];
        apt = fmaf(av, Wq1[(size_t)(NE + a) * NH + t], apt);
    }
    int nsel = (int)sam; if (nsel > NN - 1) nsel = NN - 1;
    const float yv = fp82f(y0f8[((size_t)nsel * NB + bb) * NH + t]);
    sh[t] = fmaxf(yv + apt, 0.0f) * Wq2[t];
    __syncthreads();
    for (int s = 128; s > 0; s >>= 1) {
        if (t < s) sh[t] += sh[t + s];
        __syncthreads();
    }
    if (t == 0) out[bb * NA + (NA - 1)] = sh[0] + bq2[0];
    if (t < NA) {
        const float av = (t == NA - 1) ? samn : actions[bb * NA + t];
        out[NB * NA + bb * NA + t] = (float)(int)(av * ACTION_NORM);
    }
}

// ---------------------------------------------------------------- launch
extern "C" void kernel_launch(void* const* d_in, const int* in_sizes, int n_in,
                              void* d_out, int out_size, void* d_ws, size_t ws_size,
                              hipStream_t stream) {
    const float* state = (const float*)d_in[0];
    const float* dm    = (const float*)d_in[1];
    const float* W1    = (const float*)d_in[2];
    const float* b1    = (const float*)d_in[3];
    const float* W2    = (const float*)d_in[4];
    const float* b2    = (const float*)d_in[5];
    const float* Wq1   = (const float*)d_in[6];
    const float* bq1   = (const float*)d_in[7];
    const float* Wq2   = (const float*)d_in[8];
    const float* bq2   = (const float*)d_in[9];
    const int* fa      = (const int*)d_in[10];
    const int* fid     = (const int*)d_in[11];
    float* out = (float*)d_out;

    char* p = (char*)d_ws;
    u8* simb       = (u8*)p;       p += (size_t)NN * KP8;           // 4.10 MB
    u8* encb       = (u8*)p;       p += (size_t)4096 * KP8;         // 8.39 MB
    float* inv_rs  = (float*)p;    p += 2048 * 4;
    float* pmax    = (float*)p;    p += 1024 * 4;
    float* actions = (float*)p;    p += 256 * 4;
    float* ap0     = (float*)p;    p += 8192 * 4;
    float* apbA    = (float*)p;    p += 8192 * 4;
    float* apbB    = (float*)p;    p += 8192 * 4;
    float2* part0  = (float2*)p;   p += (size_t)NB * NGP * 8;
    float2* part1  = (float2*)p;   p += (size_t)NB * NGP * 8;
    u16* state_b   = (u16*)p;      p += (size_t)2048000 * 2;
    u16* W1t       = (u16*)p;      p += 8192 * 2;
    u16* W2t       = (u16*)p;      p += 32768 * 2;
    u8* Wq1f8      = (u8*)p;       p += 32768;
    u8* y0f8       = (u8*)p;       p += (size_t)2048 * NB * NH;     // 16.78 MB (PADDED to 2048 rows)

    k_front<<<PREP_BLOCKS + MAX_BLOCKS + 1, 256, 0, stream>>>(
        state, W1, W2, Wq1, dm, fa, fid,
        state_b, W1t, W2t, Wq1f8, encb, pmax, actions, ap0, part0);
    // sim + enc
    k_sim<<<NN, 512, 0, stream>>>(dm, pmax, simb, inv_rs);
    k_enc<<<1000, 512, 0, stream>>>(state_b, W1t, W2t, encb, b1, b2);
    // fused conv + y0 + agent-0 partials (XCD-swizzled, REGISTER-staged K-loop)
    k_conv_y0<<<dim3(16, 32), 512, 0, stream>>>(simb, encb, Wq1f8, inv_rs, bq1,
                                                ap0, Wq2, y0f8, part0);
    // agents 1..7; apbase ping-pong carries the action projection forward
    for (int ag = 1; ag < NA; ++ag) {
        const float2* pin  = (ag & 1) ? part0 : part1;
        float2*       pout = (ag & 1) ? part1 : part0;
        const float*  apb  = (ag == 1) ? ap0 : ((ag & 1) ? apbB : apbA);
        float*        apo  = (ag & 1) ? apbA : apbB;
        k_agent<<<1024, 256, 0, stream>>>(y0f8, Wq1, Wq2, bq2, actions,
                                          fa, fid, apb, apo,
                                          pin, pout, out, ag);
    }
    // finalize agent 7 (+ chosen); ag=7 wrote part1
    k_fin<<<NB, 256, 0, stream>>>(y0f8, Wq1, Wq2, bq2, actions, part1, out);
}

// Round 13
// 222.373 us; speedup vs baseline: 1.2427x; 1.2427x over previous
//
#include <hip/hip_runtime.h>
#include <cstddef>

#define NB 32
#define NN 2000
#define NRD 32
#define NE 128
#define NH 256
#define NA 8
#define KP8 2048         // conv K padded (fp8, BK=64)
#define NGP 128          // partial slots per batch
#define H1S 264          // h1 LDS tile stride (u16)
#define XT8S 136         // X fp8 LDS tile stride (bytes): 34 dw -> <=2-way banks
#define ACTION_NORM 2000.0f

typedef unsigned short u16;
typedef unsigned char u8;
typedef __bf16 b16x8 __attribute__((ext_vector_type(8)));
typedef float f32x4 __attribute__((ext_vector_type(4)));
typedef const __attribute__((address_space(1))) unsigned int* gptr_t;
typedef __attribute__((address_space(3))) unsigned int* lptr_t;

__device__ inline u16 f2bf(float x) {
    unsigned u = __float_as_uint(x);
    u += 0x7FFFu + ((u >> 16) & 1u);
    return (u16)(u >> 16);
}
__device__ inline float bf2f(u16 h) { return __uint_as_float((unsigned)h << 16); }
__device__ inline u8 f2fp8(float x) {
    return (u8)(__builtin_amdgcn_cvt_pk_fp8_f32(x, x, 0, false) & 0xFF);
}
__device__ inline u16 f2fp8x2(float a, float b) {
    return (u16)(__builtin_amdgcn_cvt_pk_fp8_f32(a, b, 0, false) & 0xFFFF);
}
__device__ inline float fp82f(u8 b) {
    return __builtin_amdgcn_cvt_pk_f32_fp8((unsigned)b, false)[0];
}
// fp8 K-swizzle for conv staging (R10-verified conflict-free b128 reads)
__device__ inline int kswz(int m) {
    return (m & ~63) + (((m >> 3) & 3) << 4) + (((m >> 5) & 1) << 3) + (m & 7);
}

// ---------------------------------------------------------------- front: prep + dm partial max + actions/ap0/part0 init
#define PREP_STATE (64000 * 32)
#define PREP_W1T   (256 * 32)
#define PREP_W2T   (128 * 256)
#define PREP_WQ1T  (256 * 128)
#define PREP_PAD   (4096 * 48)
#define PREP_TOT   (PREP_STATE + PREP_W1T + PREP_W2T + PREP_WQ1T + PREP_PAD)
#define PREP_BLOCKS (PREP_TOT / 256)       // 9056
#define MAX_BLOCKS 1024
__global__ __launch_bounds__(256) void k_front(
        const float* __restrict__ state, const float* __restrict__ W1,
        const float* __restrict__ W2, const float* __restrict__ Wq1,
        const float* __restrict__ dm, const int* __restrict__ fa,
        const int* __restrict__ fid,
        u16* __restrict__ state_b, u16* __restrict__ W1t,
        u16* __restrict__ W2t, u8* __restrict__ Wq1f8,
        u8* __restrict__ encb, float* __restrict__ pmax,
        float* __restrict__ actions, float* __restrict__ ap0,
        float2* __restrict__ part0) {
    __shared__ float sh[256];
    const int blk = blockIdx.x, t = threadIdx.x;
    if (blk < PREP_BLOCKS) {
        int i = blk * 256 + t;
        if (i < PREP_STATE) { state_b[i] = f2bf(state[i]); return; }
        i -= PREP_STATE;
        if (i < PREP_W1T) { int h = i >> 5, k = i & 31; W1t[i] = f2bf(W1[k * NH + h]); return; }
        i -= PREP_W1T;
        if (i < PREP_W2T) { int e = i >> 8, h = i & 255; W2t[i] = f2bf(W2[h * NE + e]); return; }
        i -= PREP_W2T;
        if (i < PREP_WQ1T) { int hq = i >> 7, e = i & 127; Wq1f8[i] = f2fp8(Wq1[e * NH + hq]); return; }
        i -= PREP_WQ1T;
        if (i < PREP_PAD) { int eb = i / 48, mm = NN + (i % 48); encb[(size_t)eb * KP8 + kswz(mm)] = 0; }
        return;
    }
    if (blk < PREP_BLOCKS + MAX_BLOCKS) {
        const int bid = blk - PREP_BLOCKS;
        float m = 0.0f;
        for (size_t i = (size_t)bid * 256 + t; i < (size_t)NN * NN; i += (size_t)MAX_BLOCKS * 256)
            m = fmaxf(m, dm[i]);
        sh[t] = m; __syncthreads();
        for (int s = 128; s > 0; s >>= 1) {
            if (t < s) sh[t] = fmaxf(sh[t], sh[t + s]);
            __syncthreads();
        }
        if (t == 0) pmax[bid] = sh[0];
        return;
    }
    // last block: actions init + agent-0 ap + zero part0
    const int b = t >> 3, a = t & 7;
    float v = -1.0f;
    for (int j = 0; j < 3; ++j)
        if (fid[j] == a) v = (float)fa[j * NB + b] / ACTION_NORM;
    actions[t] = v;
    sh[t] = v;
    __syncthreads();
    float wq[NA];
#pragma unroll
    for (int aa = 0; aa < NA; ++aa) wq[aa] = Wq1[(size_t)(NE + aa) * NH + t];
    for (int bb = 0; bb < NB; ++bb) {
        float s = 0.0f;
#pragma unroll
        for (int aa = 0; aa < NA; ++aa) s = fmaf(sh[bb * NA + aa], wq[aa], s);
        ap0[bb * NH + t] = s;
    }
    for (int i = t; i < NB * NGP; i += 256) part0[i] = make_float2(0.0f, 0.0f);
}

// ---------------------------------------------------------------- sim: row-softmax-prep of distance matrix (grid 2000)
__global__ __launch_bounds__(512) void k_sim(
        const float* __restrict__ dm, const float* __restrict__ pmax,
        u8* __restrict__ simb, float* __restrict__ inv_rs) {
    __shared__ float shf[512];
    __shared__ u8 srow[KP8];
    const int n = blockIdx.x, t = threadIdx.x;
    float m = fmaxf(pmax[t], pmax[t + 512]);
    shf[t] = m; __syncthreads();
    for (int s = 256; s > 0; s >>= 1) {
        if (t < s) shf[t] = fmaxf(shf[t], shf[t + s]);
        __syncthreads();
    }
    const float inv = 1.0f / shf[0];
    __syncthreads();
    float s = 0.0f;
    for (int mm = t * 2; mm < KP8; mm += 1024) {
        float e0 = 0.0f, e1 = 0.0f;
        if (mm < NN)     { e0 = expf(-dm[(size_t)n * NN + mm] * inv);     s += e0; }
        if (mm + 1 < NN) { e1 = expf(-dm[(size_t)n * NN + mm + 1] * inv); s += e1; }
        *(u16*)(srow + kswz(mm)) = f2fp8x2(e0, e1);
    }
    shf[t] = s; __syncthreads();
    for (int st = 256; st > 0; st >>= 1) {
        if (t < st) shf[t] += shf[t + st];
        __syncthreads();
    }
    if (t == 0) inv_rs[n] = 1.0f / shf[0];
    // coalesced row store (srow visible via the reduction-tree barriers)
    if (t < 128) *(uint4*)(simb + (size_t)n * KP8 + t * 16) = *(const uint4*)(srow + t * 16);
}

// ---------------------------------------------------------------- enc: fused enc1+enc2 (grid 1000)
__global__ __launch_bounds__(512) void k_enc(
        const u16* __restrict__ state_b, const u16* __restrict__ W1t,
        const u16* __restrict__ W2t, u8* __restrict__ encb,
        const float* __restrict__ b1, const float* __restrict__ b2) {
    __shared__ u16 stage[20 * 512];        // 20 KB staging (phase2: 2x 8KB dbuf; epilogue: 8KB etile)
    __shared__ u16 h1t[64 * H1S];          // 33 KB h1 tile
    const int blk = blockIdx.x, tid = threadIdx.x;
    const int w = tid >> 6, l = tid & 63;
    const int lm = l & 15, lq = l >> 4;
    const int gm = blk * 64;

    // ---- phase 1: h1 tile (M=64, N=256, K=32).
    {
#pragma unroll
        for (int i = 0; i < 3; ++i) {
            const int idx = w * 3 + i;
            if (idx < 20) {
                const u16* gp;
                if (idx < 4) gp = state_b + (size_t)(gm + idx * 16 + lm) * NRD + lq * 8;
                else         gp = W1t + (size_t)((idx - 4) * 16 + lm) * NRD + lq * 8;
                __builtin_amdgcn_global_load_lds((gptr_t)gp, (lptr_t)(stage + idx * 512), 16, 0, 0);
            }
        }
        __syncthreads();
        b16x8 af[4], bf[2];
#pragma unroll
        for (int i = 0; i < 4; ++i) af[i] = *(const b16x8*)(stage + i * 512 + l * 8);
#pragma unroll
        for (int j = 0; j < 2; ++j) bf[j] = *(const b16x8*)(stage + (4 + w * 2 + j) * 512 + l * 8);
        f32x4 acc1[4][2] = {};
#pragma unroll
        for (int i = 0; i < 4; ++i)
#pragma unroll
            for (int j = 0; j < 2; ++j)
                acc1[i][j] = __builtin_amdgcn_mfma_f32_16x16x32_bf16(af[i], bf[j], acc1[i][j], 0, 0, 0);
#pragma unroll
        for (int i = 0; i < 4; ++i)
#pragma unroll
            for (int r = 0; r < 4; ++r) {
                const int row = i * 16 + lq * 4 + r;
#pragma unroll
                for (int j = 0; j < 2; ++j) {
                    const int col = w * 32 + j * 16 + lm;
                    h1t[row * H1S + col] = f2bf(fmaxf(acc1[i][j][r] + b1[col], 0.0f));
                }
            }
    }

    // ---- phase 2: enc tile (M=128 e, N=64 m, K=256), A=W2t staged (2-phase dbuf), B=h1t LDS.
    const int wr = w & 3, wc = w >> 2;
    f32x4 acc2[2][2] = {};
    const u16* gpw = W2t + (size_t)(w * 16 + lm) * NH + lq * 8;
    __syncthreads();   // phase-1 stage reads done before overwrite
    __builtin_amdgcn_global_load_lds((gptr_t)gpw, (lptr_t)(stage + w * 512), 16, 0, 0);
    __syncthreads();   // buf0 ready (+ h1t visible)
    for (int t = 0; t < 8; ++t) {
        const int cur = t & 1;
        if (t < 7) {
            gpw += 32;
            __builtin_amdgcn_global_load_lds((gptr_t)gpw,
                (lptr_t)(stage + (cur ^ 1) * 4096 + w * 512), 16, 0, 0);
        }
        const u16* base = stage + cur * 4096;
        b16x8 af2[2], bf2[2];
#pragma unroll
        for (int i = 0; i < 2; ++i)
            af2[i] = *(const b16x8*)(base + (wr * 2 + i) * 512 + l * 8);
#pragma unroll
        for (int j = 0; j < 2; ++j)
            bf2[j] = *(const b16x8*)(h1t + (wc * 32 + j * 16 + lm) * H1S + t * 32 + lq * 8);
#pragma unroll
        for (int i = 0; i < 2; ++i)
#pragma unroll
            for (int j = 0; j < 2; ++j)
                acc2[i][j] = __builtin_amdgcn_mfma_f32_16x16x32_bf16(af2[i], bf2[j], acc2[i][j], 0, 0, 0);
        __syncthreads();
    }

    // ---- epilogue: stage fp8 tile [e:128][off:64] in LDS, then coalesced writes.
    u8* etile = (u8*)stage;            // 8 KB, stage is dead after the loop's final barrier
#pragma unroll
    for (int i = 0; i < 2; ++i)
#pragma unroll
        for (int r = 0; r < 4; ++r) {
            const int e = wr * 32 + i * 16 + lq * 4 + r;
            const float bias = b2[e];
#pragma unroll
            for (int j = 0; j < 2; ++j) {
                const int off = wc * 32 + j * 16 + lm;
                etile[e * 64 + off] = f2fp8(acc2[i][j][r] + bias);
            }
        }
    __syncthreads();
#pragma unroll
    for (int u0 = 0; u0 < 2; ++u0) {
        const int u = u0 * 512 + tid;          // 1024 units: e = u>>3, run = u&7
        const int e = u >> 3, run = u & 7;
        const int rg0 = gm + run * 8;
        const unsigned bb = (unsigned)rg0 / 2000u;
        const unsigned m0 = (unsigned)rg0 - bb * 2000u;   // 8-aligned
        const int wbyte = (int)(m0 & ~63u) + (int)(((m0 >> 3) & 3u) << 4) + (int)(((m0 >> 5) & 1u) << 3);
        const uint2 v = *(const uint2*)(etile + e * 64 + run * 8);
        *(uint2*)(encb + ((size_t)bb * 128 + e) * KP8 + wbyte) = v;
    }
}

// ---------------------------------------------------------------- fused conv + y0 + agent-0 softmax partials
// R9/R11 configuration (verified 52.3 us, best measured): grid (16,32),
// 128-row tiles, XCD-aware bijective swizzle (FETCH 35->16.5 MB),
// TRIPLE-buffered global_load_lds staging with barrier AFTER compute:
//   STAGE(t+2) ; COMPUTE(t) ; vmcnt(2) ; s_barrier
// Read guarantee: step t-1's vmcnt(2) + barrier => tile-t loads landed.
// WAR guarantee: buf B rewritten only post-barrier covering its last reads.
// Ledger: counted-vmcnt +8%; swizzle FETCH -53%; occupancy/tile-shrink/
// register-staging all null-or-negative (R9/R10/R12) -> this is the local
// optimum at this tile shape.
__global__ __launch_bounds__(512) void k_conv_y0(
        const u8* __restrict__ simb, const u8* __restrict__ encb,
        const u8* __restrict__ Wq1f8, const float* __restrict__ inv_rs,
        const float* __restrict__ bq1, const float* __restrict__ ap0,
        const float* __restrict__ Wq2, u8* __restrict__ y0f8,
        float2* __restrict__ part0) {
    __shared__ u8 lds[3 * 16384];           // 48 KB triple-buffered staging; xt8 aliases base after K-loop
    __shared__ float qsum[64 * 8];          // 2 KB per-row wave partials
    const int tid = threadIdx.x;
    const int w = tid >> 6, l = tid & 63;   // 8 waves
    const int wr = w & 1, wc = w >> 1;      // wc in [0,4)
    // ---- XCD-aware bijective block remap
    const int L = blockIdx.x + (int)(blockIdx.y << 4);
    const int g = L & 7, ii = L >> 3;
    const int bx = (g & 1) * 8 + (ii & 7);       // node tile 0..15
    const int by = (g >> 1) * 8 + (ii >> 3);     // batch 0..31
    const int bm = bx * 128;
    const int bb = by;
    const int lm = l & 15, lq = l >> 4;
    const u8* Bt = encb + (size_t)bb * 128 * KP8;
    typedef long lx2 __attribute__((ext_vector_type(2)));

    f32x4 acc[4][2] = {};

    const u8* gpt[2];
#pragma unroll
    for (int i = 0; i < 2; ++i) {
        const int idx = w * 2 + i;
        if (idx < 8) {
            int row = bm + idx * 16 + lm;
            row = row < NN ? row : NN - 1;
            gpt[i] = simb + (size_t)row * KP8 + lq * 16;
        } else {
            gpt[i] = Bt + (size_t)((idx - 8) * 16 + lm) * KP8 + lq * 16;
        }
    }

    auto STAGE = [&](int kt, int buf) {
#pragma unroll
        for (int i = 0; i < 2; ++i)
            __builtin_amdgcn_global_load_lds((gptr_t)(gpt[i] + kt * 64),
                (lptr_t)(lds + buf * 16384 + (w * 2 + i) * 1024), 16, 0, 0);
    };
    auto COMPUTE = [&](int buf) {
        const u8* curb = lds + buf * 16384;
        const int fo = l * 16;              // lane-linear b128: conflict-free
        lx2 af[4], bf[2];
#pragma unroll
        for (int i = 0; i < 4; ++i)
            af[i] = *(const lx2*)(curb + (wr * 4 + i) * 1024 + fo);
#pragma unroll
        for (int j = 0; j < 2; ++j)
            bf[j] = *(const lx2*)(curb + (8 + wc * 2 + j) * 1024 + fo);
        __builtin_amdgcn_s_setprio(1);
#pragma unroll
        for (int i = 0; i < 4; ++i)
#pragma unroll
            for (int j = 0; j < 2; ++j) {
                acc[i][j] = __builtin_amdgcn_mfma_f32_16x16x32_fp8_fp8(af[i][0], bf[j][0], acc[i][j], 0, 0, 0);
                acc[i][j] = __builtin_amdgcn_mfma_f32_16x16x32_fp8_fp8(af[i][1], bf[j][1], acc[i][j], 0, 0, 0);
            }
        __builtin_amdgcn_s_setprio(0);
    };

#define FENCE() __builtin_amdgcn_sched_barrier(0)
#define WAIT_VM(N) do { FENCE(); asm volatile("s_waitcnt vmcnt(" #N ")" ::: "memory"); FENCE(); } while (0)
#define BARRIER() do { FENCE(); __builtin_amdgcn_s_barrier(); FENCE(); } while (0)

    // prologue: stage tiles 0,1; tile 0 landed everywhere before step 0
    STAGE(0, 0);
    STAGE(1, 1);
    WAIT_VM(2); BARRIER();
    // main loop t = 0..29
    for (int t = 0; t < 30; ++t) {
        STAGE(t + 2, (t + 2) % 3);     // outstanding: tiles t+1, t+2
        COMPUTE(t % 3);                // tile t (guaranteed by barrier t-1)
        WAIT_VM(2); BARRIER();         // tile t+1 landed; buf[t%3] reads retired
    }
    // t = 30 (tile 31 in flight)
    COMPUTE(0);                        // 30 % 3
    WAIT_VM(0); BARRIER();             // tile 31 landed
    // t = 31
    COMPUTE(1);                        // 31 % 3
    BARRIER();                         // xt8 alias overwrite: all buf reads retired
#undef WAIT_VM
#undef BARRIER
#undef FENCE

    // ---- epilogue 1: scaled X tile -> fp8 LDS (aliased over dead staging buffers)
#pragma unroll
    for (int i = 0; i < 4; ++i) {
#pragma unroll
        for (int r = 0; r < 4; ++r) {
            const int row = wr * 64 + i * 16 + lq * 4 + r;
            const int gn = bm + row;
            const float rsv = inv_rs[gn < NN ? gn : NN - 1];
#pragma unroll
            for (int j = 0; j < 2; ++j) {
                const int col = wc * 32 + j * 16 + lm;
                lds[row * XT8S + col] = f2fp8(acc[i][j][r] * rsv);
            }
        }
    }
    __syncthreads();

    // ---- phase 2+3: y0 (fp8 MFMA) + agent-0 q partials
    const int h0 = w * 32;
    float bq1v[2], apv[2], w2vv[2];
#pragma unroll
    for (int j = 0; j < 2; ++j) {
        const int h = h0 + j * 16 + lm;
        bq1v[j] = bq1[h];
        apv[j] = ap0[bb * NH + h];
        w2vv[j] = Wq2[h];
    }
    float se_tot = 0.0f, sn_tot = 0.0f;

    for (int half = 0; half < 2; ++half) {
        f32x4 acc2[4][2] = {};
#pragma unroll
        for (int ks = 0; ks < 4; ++ks) {
            long bfw[2];
#pragma unroll
            for (int j = 0; j < 2; ++j)
                bfw[j] = *(const long*)(Wq1f8 + (size_t)(h0 + j * 16 + lm) * NE + ks * 32 + lq * 8);
#pragma unroll
            for (int i = 0; i < 4; ++i) {
                const long afx = *(const long*)(lds + (half * 64 + i * 16 + lm) * XT8S + ks * 32 + lq * 8);
#pragma unroll
                for (int j = 0; j < 2; ++j)
                    acc2[i][j] = __builtin_amdgcn_mfma_f32_16x16x32_fp8_fp8(afx, bfw[j], acc2[i][j], 0, 0, 0);
            }
        }
#pragma unroll
        for (int i = 0; i < 4; ++i) {
#pragma unroll
            for (int r = 0; r < 4; ++r) {
                const int rl = i * 16 + lq * 4 + r;
                const int n = bm + half * 64 + rl;
                float q = 0.0f;
#pragma unroll
                for (int j = 0; j < 2; ++j) {
                    const float v = acc2[i][j][r] + bq1v[j];
                    if (n < NN) y0f8[((size_t)n * NB + bb) * NH + h0 + j * 16 + lm] = f2fp8(v);
                    q += fmaxf(v + apv[j], 0.0f) * w2vv[j];
                }
#pragma unroll
                for (int off = 1; off < 16; off <<= 1) q += __shfl_xor(q, off);
                if (lm == 0) qsum[rl * 8 + w] = q;
            }
        }
        __syncthreads();
        if (tid < 64) {
            const int n = bm + half * 64 + tid;
            float q = 0.0f;
#pragma unroll
            for (int wv = 0; wv < 8; ++wv) q += qsum[tid * 8 + wv];
            float e = (n < NN) ? expf(fminf(q, 60.0f)) : 0.0f;
            float sne = e * (float)n;
#pragma unroll
            for (int off = 32; off > 0; off >>= 1) {
                e += __shfl_xor(e, off); sne += __shfl_xor(sne, off);
            }
            if (tid == 0) { se_tot += e; sn_tot += sne; }
        }
        __syncthreads();
    }
    if (tid == 0) part0[bb * NGP + bx] = make_float2(se_tot, sn_tot);
}

// ---------------------------------------------------------------- per-agent kernel (ag = 1..7)
// y0f8 padded to 2048 rows: 4 unconditional main-loop loads hoisted to the TOP
// (independent of the pin reduce -> overlap HBM latency with the reduction).
// ap16 = apb (carried projection) + d * Wq1[agent row] (R7-verified).
__global__ __launch_bounds__(256) void k_agent(
        const u8* __restrict__ y0f8, const float* __restrict__ Wq1,
        const float* __restrict__ Wq2, const float* __restrict__ bq2,
        float* actions, const int* __restrict__ fa, const int* __restrict__ fid,
        const float* __restrict__ apb, float* __restrict__ apbase_out,
        const float2* __restrict__ pin, float2* __restrict__ pout,
        float* __restrict__ out, int ag) {
    __shared__ float sh[256];
    __shared__ float s_sam;
    const int t = threadIdx.x;
    const int lane = t & 63, wave = t >> 6;
    const int wg = blockIdx.x * 4 + wave;
    const int b = wg & 31, ng = wg >> 5;        // ng in [0,128)
    const int hl = lane & 15, qtr = lane >> 4;
    const int idx = ag - 1;

    // ---- y0 loads FIRST (no dependency on pin): HBM latency overlaps reduce
    uint4 yv[4];
#pragma unroll
    for (int k = 0; k < 4; ++k) {
        const int n = 4 * (ng + k * NGP) + qtr;     // < 2048 (padded)
        yv[k] = *(const uint4*)(y0f8 + (((size_t)n * NB + b) << 8) + hl * 16);
    }

    float samn;
    {
        const float2 p0 = pin[b * NGP + lane];
        const float2 p1 = pin[b * NGP + 64 + lane];
        float se0 = p0.x + p1.x, sn0 = p0.y + p1.y;
#pragma unroll
        for (int m = 32; m > 0; m >>= 1) {
            se0 += __shfl_xor(se0, m); sn0 += __shfl_xor(sn0, m);
        }
        const float sam = fminf(fmaxf(sn0 / se0, 0.0f), 2000.0f);
        samn = sam * (1.0f / ACTION_NORM);
    }
    // initial action value for this agent slot (never yet written to actions[])
    float iv = -1.0f;
    for (int j = 0; j < 3; ++j)
        if (fid[j] == idx) iv = (float)fa[j * NB + b] * (1.0f / ACTION_NORM);
    const float d = samn - iv;

    float ap16[16], w2v[16];
    {
        const float4* ab  = (const float4*)(apb + b * NH + hl * 16);
        const float4* wq  = (const float4*)(Wq1 + (size_t)(NE + idx) * NH + hl * 16);
        const float4* w2p = (const float4*)(Wq2 + hl * 16);
#pragma unroll
        for (int jj = 0; jj < 4; ++jj) {
            const float4 a4 = ab[jj]; const float4 w4 = wq[jj]; const float4 v4 = w2p[jj];
            ap16[jj * 4 + 0] = fmaf(d, w4.x, a4.x);
            ap16[jj * 4 + 1] = fmaf(d, w4.y, a4.y);
            ap16[jj * 4 + 2] = fmaf(d, w4.z, a4.z);
            ap16[jj * 4 + 3] = fmaf(d, w4.w, a4.w);
            w2v[jj * 4 + 0] = v4.x; w2v[jj * 4 + 1] = v4.y;
            w2v[jj * 4 + 2] = v4.z; w2v[jj * 4 + 3] = v4.w;
        }
    }

    float se = 0.0f, sn = 0.0f;
#pragma unroll
    for (int k = 0; k < 4; ++k) {
        const int n = 4 * (ng + k * NGP) + qtr;
        const unsigned dw[4] = {yv[k].x, yv[k].y, yv[k].z, yv[k].w};
        float q = 0.0f;
#pragma unroll
        for (int dd = 0; dd < 4; ++dd) {
            const auto lo = __builtin_amdgcn_cvt_pk_f32_fp8(dw[dd], false);
            const auto hi = __builtin_amdgcn_cvt_pk_f32_fp8(dw[dd], true);
            q += fmaxf(lo[0] + ap16[dd * 4 + 0], 0.f) * w2v[dd * 4 + 0];
            q += fmaxf(lo[1] + ap16[dd * 4 + 1], 0.f) * w2v[dd * 4 + 1];
            q += fmaxf(hi[0] + ap16[dd * 4 + 2], 0.f) * w2v[dd * 4 + 2];
            q += fmaxf(hi[1] + ap16[dd * 4 + 3], 0.f) * w2v[dd * 4 + 3];
        }
#pragma unroll
        for (int off = 1; off < 16; off <<= 1) q += __shfl_xor(q, off);
        if (n < NN) {
            const float e = expf(fminf(q, 60.0f));
            se += e; sn += e * (float)n;
        }
    }
    se += __shfl_xor(se, 16); sn += __shfl_xor(sn, 16);
    se += __shfl_xor(se, 32); sn += __shfl_xor(sn, 32);
    if (lane == 0) pout[b * NGP + ng] = make_float2(se, sn);

    if (blockIdx.x < NB) {
        const int bb = blockIdx.x;
        if (wave == 0) {
            const float2 p0 = pin[bb * NGP + lane];
            const float2 p1 = pin[bb * NGP + 64 + lane];
            float a1 = p0.x + p1.x, a2 = p0.y + p1.y;
#pragma unroll
            for (int m = 32; m > 0; m >>= 1) {
                a1 += __shfl_xor(a1, m); a2 += __shfl_xor(a2, m);
            }
            if (lane == 0) s_sam = fminf(fmaxf(a2 / a1, 0.0f), 2000.0f);
        }
        __syncthreads();
        const float sam = s_sam;
        const float samf = sam * (1.0f / ACTION_NORM);
        float apt = 0.0f;
#pragma unroll
        for (int a = 0; a < NA; ++a) {
            const float av = (a == idx) ? samf : actions[bb * NA + a];
            apt = fmaf(av, Wq1[(size_t)(NE + a) * NH + t], apt);
        }
        apbase_out[bb * NH + t] = apt;          // carried projection for stage ag+1
        int nsel = (int)sam; if (nsel > NN - 1) nsel = NN - 1;
        const float yv2 = fp82f(y0f8[((size_t)nsel * NB + bb) * NH + t]);
        sh[t] = fmaxf(yv2 + apt, 0.0f) * Wq2[t];
        __syncthreads();
        for (int s = 128; s > 0; s >>= 1) {
            if (t < s) sh[t] += sh[t + s];
            __syncthreads();
        }
        if (t == 0) {
            out[bb * NA + idx] = sh[0] + bq2[0];
            actions[bb * NA + idx] = samf;
        }
    }
}

// ---------------------------------------------------------------- tail: finalize agent 7 + chosen
__global__ __launch_bounds__(256) void k_fin(
        const u8* __restrict__ y0f8, const float* __restrict__ Wq1,
        const float* __restrict__ Wq2, const float* __restrict__ bq2,
        const float* __restrict__ actions, const float2* __restrict__ pin,
        float* __restrict__ out) {
    __shared__ float sh[256];
    __shared__ float s_sam;
    const int bb = blockIdx.x, t = threadIdx.x;
    const int lane = t & 63, wave = t >> 6;
    if (wave == 0) {
        const float2 p0 = pin[bb * NGP + lane];
        const float2 p1 = pin[bb * NGP + 64 + lane];
        float a1 = p0.x + p1.x, a2 = p0.y + p1.y;
#pragma unroll
        for (int m = 32; m > 0; m >>= 1) {
            a1 += __shfl_xor(a1, m); a2 += __shfl_xor(a2, m);
        }
        if (lane == 0) s_sam = fminf(fmaxf(a2 / a1, 0.0f), 2000.0f);
    }
    __syncthreads();
    const float sam = s_sam;
    const float samn = sam * (1.0f / ACTION_NORM);
    float apt = 0.0f;
#pragma unroll
    for (int a = 0; a < NA; ++a) {
        const float av = (a == NA - 1) ? samn : actions[bb * NA + a];
        apt = fmaf(av, Wq1[(size_t)(NE + a) * NH + t], apt);
    }
    int nsel = (int)sam; if (nsel > NN - 1) nsel = NN - 1;
    const float yv = fp82f(y0f8[((size_t)nsel * NB + bb) * NH + t]);
    sh[t] = fmaxf(yv + apt, 0.0f) * Wq2[t];
    __syncthreads();
    for (int s = 128; s > 0; s >>= 1) {
        if (t < s) sh[t] += sh[t + s];
        __syncthreads();
    }
    if (t == 0) out[bb * NA + (NA - 1)] = sh[0] + bq2[0];
    if (t < NA) {
        const float av = (t == NA - 1) ? samn : actions[bb * NA + t];
        out[NB * NA + bb * NA + t] = (float)(int)(av * ACTION_NORM);
    }
}

// ---------------------------------------------------------------- launch
extern "C" void kernel_launch(void* const* d_in, const int* in_sizes, int n_in,
                              void* d_out, int out_size, void* d_ws, size_t ws_size,
                              hipStream_t stream) {
    const float* state = (const float*)d_in[0];
    const float* dm    = (const float*)d_in[1];
    const float* W1    = (const float*)d_in[2];
    const float* b1    = (const float*)d_in[3];
    const float* W2    = (const float*)d_in[4];
    const float* b2    = (const float*)d_in[5];
    const float* Wq1   = (const float*)d_in[6];
    const float* bq1   = (const float*)d_in[7];
    const float* Wq2   = (const float*)d_in[8];
    const float* bq2   = (const float*)d_in[9];
    const int* fa      = (const int*)d_in[10];
    const int* fid     = (const int*)d_in[11];
    float* out = (float*)d_out;

    char* p = (char*)d_ws;
    u8* simb       = (u8*)p;       p += (size_t)NN * KP8;           // 4.10 MB
    u8* encb       = (u8*)p;       p += (size_t)4096 * KP8;         // 8.39 MB
    float* inv_rs  = (float*)p;    p += 2048 * 4;
    float* pmax    = (float*)p;    p += 1024 * 4;
    float* actions = (float*)p;    p += 256 * 4;
    float* ap0     = (float*)p;    p += 8192 * 4;
    float* apbA    = (float*)p;    p += 8192 * 4;
    float* apbB    = (float*)p;    p += 8192 * 4;
    float2* part0  = (float2*)p;   p += (size_t)NB * NGP * 8;
    float2* part1  = (float2*)p;   p += (size_t)NB * NGP * 8;
    u16* state_b   = (u16*)p;      p += (size_t)2048000 * 2;
    u16* W1t       = (u16*)p;      p += 8192 * 2;
    u16* W2t       = (u16*)p;      p += 32768 * 2;
    u8* Wq1f8      = (u8*)p;       p += 32768;
    u8* y0f8       = (u8*)p;       p += (size_t)2048 * NB * NH;     // 16.78 MB (PADDED to 2048 rows)

    k_front<<<PREP_BLOCKS + MAX_BLOCKS + 1, 256, 0, stream>>>(
        state, W1, W2, Wq1, dm, fa, fid,
        state_b, W1t, W2t, Wq1f8, encb, pmax, actions, ap0, part0);
    // sim + enc
    k_sim<<<NN, 512, 0, stream>>>(dm, pmax, simb, inv_rs);
    k_enc<<<1000, 512, 0, stream>>>(state_b, W1t, W2t, encb, b1, b2);
    // fused conv + y0 + agent-0 partials (XCD-swizzled, triple-buffered, 128-row tiles)
    k_conv_y0<<<dim3(16, 32), 512, 0, stream>>>(simb, encb, Wq1f8, inv_rs, bq1,
                                                ap0, Wq2, y0f8, part0);
    // agents 1..7; apbase ping-pong carries the action projection forward
    for (int ag = 1; ag < NA; ++ag) {
        const float2* pin  = (ag & 1) ? part0 : part1;
        float2*       pout = (ag & 1) ? part1 : part0;
        const float*  apb  = (ag == 1) ? ap0 : ((ag & 1) ? apbB : apbA);
        float*        apo  = (ag & 1) ? apbA : apbB;
        k_agent<<<1024, 256, 0, stream>>>(y0f8, Wq1, Wq2, bq2, actions,
                                          fa, fid, apb, apo,
                                          pin, pout, out, ag);
    }
    // finalize agent 7 (+ chosen); ag=7 wrote part1
    k_fin<<<NB, 256, 0, stream>>>(y0f8, Wq1, Wq2, bq2, actions, part1, out);
}